// Round 1
// baseline (146.653 us; speedup 1.0000x reference)
//
#include <hip/hip_runtime.h>

// Bahdanau attention + LayerNorm + residual, B=8, TX=TY=128, D=H=512, fp32.
//
// Decomposition:
//   k1 (gemm_dual): Wc = ctx@Wa, Ux = x@Ua   (biases folded downstream; bVa
//                   cancels in softmax and is dropped)
//   k2 (attn_fused): per (b, 2 ty rows): scores over tx via
//                   sum_h Va[h]*tanh(Wc+bias+Ux), softmax(tx), cv = attn@ctx,
//                   LayerNorm(cv)*gamma+beta + x.
// t [B,TY,TX,H] (268 MB) is never materialized.

#define B_   8
#define TXN  128
#define TYN  128
#define D_   512
#define H_   512

__device__ __forceinline__ float fast_tanh(float v) {
  // tanh(v) = 1 - 2/(exp(2v)+1); exact at +/-inf, ~1e-6 abs err elsewhere.
  float e = __expf(2.0f * v);
  return 1.0f - 2.0f * __builtin_amdgcn_rcpf(e + 1.0f);
}

// ---------------------------------------------------------------------------
// Dual GEMM: Y[1024,512] = X[1024,512] @ W[512,512]   (z=0: Wc, z=1: Ux)
// 64x64 tile / block, 4x4 per thread, BK=16, float4 LDS fragments.
// ---------------------------------------------------------------------------
__global__ __launch_bounds__(256) void gemm_dual(
    const float* __restrict__ ctx, const float* __restrict__ xin,
    const float* __restrict__ Wa, const float* __restrict__ Ua,
    float* __restrict__ Wc, float* __restrict__ Ux) {
  const bool second = (blockIdx.z != 0);
  const float* __restrict__ X = second ? xin : ctx;
  const float* __restrict__ W = second ? Ua : Wa;
  float* __restrict__ Y       = second ? Ux : Wc;

  const int m0 = blockIdx.x * 64;
  const int n0 = blockIdx.y * 64;

  // 68-float row pitch: 16B-aligned float4 rows + conflict-benign banks.
  __shared__ __align__(16) float As[16][68];  // As[k][m]
  __shared__ __align__(16) float Bs[16][64];  // Bs[k][n]

  const int tid = threadIdx.x;
  const int tcx = tid & 15;   // n-direction (x4)
  const int tcy = tid >> 4;   // m-direction (x4)

  float acc[4][4] = {};

  for (int kt = 0; kt < 512; kt += 16) {
#pragma unroll
    for (int l = 0; l < 4; l++) {
      const int m = (tid >> 4) + (l << 4);
      const int kk = tid & 15;
      As[kk][m] = X[(m0 + m) * 512 + kt + kk];
    }
#pragma unroll
    for (int l = 0; l < 4; l++) {
      const int kk = (tid >> 6) + (l << 2);
      const int n = tid & 63;
      Bs[kk][n] = W[(kt + kk) * 512 + n0 + n];
    }
    __syncthreads();
#pragma unroll
    for (int kk = 0; kk < 16; kk++) {
      const float4 av = *(const float4*)&As[kk][tcy * 4];
      const float4 bv = *(const float4*)&Bs[kk][tcx * 4];
      const float a[4] = {av.x, av.y, av.z, av.w};
      const float b[4] = {bv.x, bv.y, bv.z, bv.w};
#pragma unroll
      for (int i = 0; i < 4; i++)
#pragma unroll
        for (int j = 0; j < 4; j++) acc[i][j] = fmaf(a[i], b[j], acc[i][j]);
    }
    __syncthreads();
  }

#pragma unroll
  for (int i = 0; i < 4; i++) {
    float4 o = make_float4(acc[i][0], acc[i][1], acc[i][2], acc[i][3]);
    *(float4*)&Y[(m0 + tcy * 4 + i) * 512 + n0 + tcx * 4] = o;
  }
}

// ---------------------------------------------------------------------------
// Fused scores + softmax + context-vector + LayerNorm + residual.
// Block = (b, 2 consecutive ty rows); 256 threads = 4 waves.
// Grid (64, 8) = 512 blocks -> 2 blocks/CU, 2 waves/SIMD.
// ---------------------------------------------------------------------------
__global__ __launch_bounds__(256) void attn_fused(
    const float* __restrict__ Wc, const float* __restrict__ Ux,
    const float* __restrict__ ctx, const float* __restrict__ xin,
    const float* __restrict__ bWa, const float* __restrict__ bUa,
    const float* __restrict__ Va,
    const float* __restrict__ gamma, const float* __restrict__ beta,
    float* __restrict__ out) {
  const int b   = blockIdx.y;
  const int ty0 = blockIdx.x * 2;
  const int tid  = threadIdx.x;
  const int lane = tid & 63;
  const int wave = tid >> 6;

  __shared__ float  s_bias[512];
  __shared__ float  s_va[512];
  __shared__ float  s_ux[2 * 512];
  __shared__ __align__(16) float2 s_at[128];   // scores -> attn, rows (ty0, ty0+1)
  __shared__ float  s_red[2][2][4];            // [sum|sumsq][tyl][wave]
  __shared__ float  s_mv[2][2];                // [mean|rstd][tyl]

  for (int i = tid; i < 512; i += 256) {
    s_bias[i] = bWa[i] + bUa[i];   // h-only biases fold together
    s_va[i]   = Va[i];
  }
  {
    const float* uxbase = Ux + (size_t)(b * TYN + ty0) * 512;  // 2 contiguous rows
    for (int i = tid; i < 1024; i += 256) s_ux[i] = uxbase[i];
  }
  __syncthreads();

  // ---- scores: wave w owns tx in [32w, 32w+32) ----
  for (int txi = 0; txi < 32; txi++) {
    const int tx = (wave << 5) + txi;
    const float* wcrow = Wc + (size_t)(b * TXN + tx) * 512;
    float a0 = 0.f, a1 = 0.f;
#pragma unroll
    for (int k = 0; k < 8; k++) {
      const int h = lane + (k << 6);
      const float wcv = wcrow[h] + s_bias[h];
      const float va  = s_va[h];
      a0 += va * fast_tanh(wcv + s_ux[h]);
      a1 += va * fast_tanh(wcv + s_ux[512 + h]);
    }
#pragma unroll
    for (int off = 32; off; off >>= 1) {
      a0 += __shfl_xor(a0, off);
      a1 += __shfl_xor(a1, off);
    }
    if (lane == 0) s_at[tx] = make_float2(a0, a1);  // bVa cancels in softmax
  }
  __syncthreads();

  // ---- softmax over tx (waves 0,1 -> rows 0,1) ----
  if (wave < 2) {
    float* base = (float*)s_at;
    float s0 = base[lane * 2 + wave];
    float s1 = base[(lane + 64) * 2 + wave];
    float m = fmaxf(s0, s1);
#pragma unroll
    for (int off = 32; off; off >>= 1) m = fmaxf(m, __shfl_xor(m, off));
    float e0 = __expf(s0 - m);
    float e1 = __expf(s1 - m);
    float s = e0 + e1;
#pragma unroll
    for (int off = 32; off; off >>= 1) s += __shfl_xor(s, off);
    const float r = __builtin_amdgcn_rcpf(s);
    base[lane * 2 + wave] = e0 * r;
    base[(lane + 64) * 2 + wave] = e1 * r;
  }
  __syncthreads();

  // ---- context vector: thread owns d = {2*tid, 2*tid+1} ----
  const float2* ctx2 = (const float2*)ctx + (size_t)b * TXN * 256 + tid;
  float2 cv0 = {0.f, 0.f}, cv1 = {0.f, 0.f};
#pragma unroll 4
  for (int tx = 0; tx < 128; tx++) {
    const float2 c  = ctx2[tx * 256];
    const float2 at = s_at[tx];           // broadcast b64 read
    cv0.x = fmaf(at.x, c.x, cv0.x);
    cv0.y = fmaf(at.x, c.y, cv0.y);
    cv1.x = fmaf(at.y, c.x, cv1.x);
    cv1.y = fmaf(at.y, c.y, cv1.y);
  }

  // ---- layernorm stats ----
#pragma unroll
  for (int tyl = 0; tyl < 2; tyl++) {
    const float2 cv = tyl ? cv1 : cv0;
    float s = cv.x + cv.y;
    float q = cv.x * cv.x + cv.y * cv.y;
#pragma unroll
    for (int off = 32; off; off >>= 1) {
      s += __shfl_xor(s, off);
      q += __shfl_xor(q, off);
    }
    if (lane == 0) { s_red[0][tyl][wave] = s; s_red[1][tyl][wave] = q; }
  }
  __syncthreads();
  if (tid < 2) {
    const float s = s_red[0][tid][0] + s_red[0][tid][1] + s_red[0][tid][2] + s_red[0][tid][3];
    const float q = s_red[1][tid][0] + s_red[1][tid][1] + s_red[1][tid][2] + s_red[1][tid][3];
    const float mean = s * (1.0f / 512.0f);
    const float var  = q * (1.0f / 512.0f) - mean * mean;
    s_mv[0][tid] = mean;
    s_mv[1][tid] = __builtin_amdgcn_rsqf(var + 1e-3f);  // keras LN eps
  }
  __syncthreads();

  // ---- normalize + gamma/beta + residual ----
  const float2 g  = ((const float2*)gamma)[tid];
  const float2 bt = ((const float2*)beta)[tid];
#pragma unroll
  for (int tyl = 0; tyl < 2; tyl++) {
    const int row = b * TYN + ty0 + tyl;
    const float2 xv = ((const float2*)xin)[(size_t)row * 256 + tid];
    const float2 cv = tyl ? cv1 : cv0;
    const float mean = s_mv[0][tyl], rstd = s_mv[1][tyl];
    float2 o;
    o.x = (cv.x - mean) * rstd * g.x + bt.x + xv.x;
    o.y = (cv.y - mean) * rstd * g.y + bt.y + xv.y;
    ((float2*)out)[(size_t)row * 256 + tid] = o;
  }
}

extern "C" void kernel_launch(void* const* d_in, const int* in_sizes, int n_in,
                              void* d_out, int out_size, void* d_ws, size_t ws_size,
                              hipStream_t stream) {
  const float* ctx   = (const float*)d_in[0];
  const float* xin   = (const float*)d_in[1];
  const float* Wa    = (const float*)d_in[2];
  const float* bWa   = (const float*)d_in[3];
  const float* Ua    = (const float*)d_in[4];
  const float* bUa   = (const float*)d_in[5];
  const float* Va    = (const float*)d_in[6];
  // d_in[7] = bVa: additive constant on scores -> cancels in softmax.
  const float* gamma = (const float*)d_in[8];
  const float* beta  = (const float*)d_in[9];
  float* out = (float*)d_out;

  float* Wc = (float*)d_ws;            // [1024, 512] fp32 (2 MB)
  float* Ux = Wc + 1024 * 512;         // [1024, 512] fp32 (2 MB)

  gemm_dual<<<dim3(16, 8, 2), 256, 0, stream>>>(ctx, xin, Wa, Ua, Wc, Ux);
  attn_fused<<<dim3(64, 8), 256, 0, stream>>>(Wc, Ux, ctx, xin, bWa, bUa, Va,
                                              gamma, beta, out);
}

// Round 3
// 119.137 us; speedup vs baseline: 1.2310x; 1.2310x over previous
//
#include <hip/hip_runtime.h>

// Bahdanau attention + LayerNorm + residual, B=8, TX=TY=128, D=H=512, fp32 in/out.
//
// Pipeline:
//   k0 prep_transpose: Wa,Ua [k][n] fp32 -> WaT,UaT [n][k] bf16 (raw ushort bits)
//   k1 gemm_mfma (bf16 MFMA 16x16x32, 64x64 tiles):
//        z=0: WcT[b][h][tx] = (ctx@Wa + bWa + bUa) * 2        (transposed + prescaled)
//        z=1: Ux[b*128+ty][h] = (x@Ua) * 2
//   k2 attn2: scores s[ty,tx] = sumVa - 2*sum_h Va[h]/(1+exp(WcT+Ux))
//        (tanh(v) = 1 - 2/(1+e^{2v}); sumVa & bVa cancel under softmax)
//        -> softmax(tx) -> cv = attn@ctx -> LayerNorm*gamma+beta + x
// t [B,TY,TX,H] (268 MB) never materialized.

#define SCALE 2.0f   // tanh(v) needs e^{2v}; fold the 2 into Wc/Ux

typedef __attribute__((ext_vector_type(8))) short short8;
typedef float floatx4 __attribute__((ext_vector_type(4)));

__device__ __forceinline__ unsigned short f2bf(float f) {
  union { float f; unsigned u; } c{f};
  unsigned r = (c.u + 0x7FFFu + ((c.u >> 16) & 1u)) >> 16;
  return (unsigned short)r;
}

// ---------------------------------------------------------------------------
// k0: transpose+convert Wa/Ua [512k][512n] fp32 -> WT [512n][512k] bf16 bits.
// 128 blocks x 256 thr; 64x64 tiles via LDS.
// ---------------------------------------------------------------------------
__global__ __launch_bounds__(256) void prep_transpose(
    const float* __restrict__ Wa, const float* __restrict__ Ua,
    unsigned short* __restrict__ WaT, unsigned short* __restrict__ UaT) {
  const int id = blockIdx.x;
  const float* __restrict__ W = (id & 64) ? Ua : Wa;
  unsigned short* __restrict__ WT = (id & 64) ? UaT : WaT;
  const int tile = id & 63;
  const int k0 = (tile >> 3) * 64;
  const int n0 = (tile & 7) * 64;
  __shared__ float tl[64][65];
  const int t = threadIdx.x;
  const int c = t & 63, r0 = t >> 6;
#pragma unroll
  for (int p = 0; p < 16; p++) {
    const int k = r0 + p * 4;
    tl[k][c] = W[(k0 + k) * 512 + n0 + c];
  }
  __syncthreads();
  const int nl = t >> 2, kc = (t & 3) * 16;
  unsigned short ov[16];
#pragma unroll
  for (int q = 0; q < 16; q++) ov[q] = f2bf(tl[kc + q][nl]);
  *(short8*)&WT[(size_t)(n0 + nl) * 512 + k0 + kc]     = *(short8*)&ov[0];
  *(short8*)&WT[(size_t)(n0 + nl) * 512 + k0 + kc + 8] = *(short8*)&ov[8];
}

// ---------------------------------------------------------------------------
// k1: dual bf16-MFMA GEMM. C[1024,512] = A[1024,512] @ B[512,512].
// 64x64 tile/block, 4 waves 2x2, each wave 32x32 via 2x2 MFMA 16x16x32.
// Frag-major LDS: slot t holds lane-frag (8 bf16, 16B) -> conflict-free b128.
// A staged fp32->bf16 in-kernel; B pre-transposed bf16 [n][k].
// ---------------------------------------------------------------------------
__global__ __launch_bounds__(256) void gemm_mfma(
    const float* __restrict__ ctx, const float* __restrict__ xin,
    const unsigned short* __restrict__ WaT, const unsigned short* __restrict__ UaT,
    const float* __restrict__ bWa, const float* __restrict__ bUa,
    float* __restrict__ WcT, float* __restrict__ Ux) {
  const bool second = (blockIdx.z != 0);
  const float* __restrict__ A = second ? xin : ctx;
  const unsigned short* __restrict__ BT = second ? UaT : WaT;
  const int m0 = blockIdx.x * 64, n0 = blockIdx.y * 64;

  __shared__ __align__(16) unsigned short As[64 * 32];
  __shared__ __align__(16) unsigned short Bs[64 * 32];

  const int t = threadIdx.x;
  const int l = t & 63;                 // frag lane slot
  const int sub = t >> 6;               // which 16-row subtile (0..3)
  const int rl = sub * 16 + (l & 15);   // local m (or n) row
  const int kl = (l >> 4) * 8;          // k offset of this lane's frag

  const float* aptr = A + (size_t)(m0 + rl) * 512 + kl;
  const unsigned short* bptr = BT + (size_t)(n0 + rl) * 512 + kl;

  const int lane = t & 63, w = t >> 6;
  const int wrow = w >> 1, wcol = w & 1;

  floatx4 acc[2][2] = {};

  // register double-buffer prefetch
  float4 a0 = *(const float4*)(aptr);
  float4 a1 = *(const float4*)(aptr + 4);
  short8 bv = *(const short8*)(bptr);

  for (int kt = 0; kt < 512; kt += 32) {
    short8 av;
    av[0] = (short)f2bf(a0.x); av[1] = (short)f2bf(a0.y);
    av[2] = (short)f2bf(a0.z); av[3] = (short)f2bf(a0.w);
    av[4] = (short)f2bf(a1.x); av[5] = (short)f2bf(a1.y);
    av[6] = (short)f2bf(a1.z); av[7] = (short)f2bf(a1.w);
    ((short8*)As)[t] = av;
    ((short8*)Bs)[t] = bv;
    __syncthreads();
    if (kt + 32 < 512) {
      a0 = *(const float4*)(aptr + kt + 32);
      a1 = *(const float4*)(aptr + kt + 36);
      bv = *(const short8*)(bptr + kt + 32);
    }
    short8 af[2], bf[2];
    af[0] = ((const short8*)As)[(wrow * 2 + 0) * 64 + lane];
    af[1] = ((const short8*)As)[(wrow * 2 + 1) * 64 + lane];
    bf[0] = ((const short8*)Bs)[(wcol * 2 + 0) * 64 + lane];
    bf[1] = ((const short8*)Bs)[(wcol * 2 + 1) * 64 + lane];
#pragma unroll
    for (int i = 0; i < 2; i++)
#pragma unroll
      for (int j = 0; j < 2; j++)
        acc[i][j] = __builtin_amdgcn_mfma_f32_16x16x32_bf16(af[i], bf[j], acc[i][j], 0, 0, 0);
    __syncthreads();
  }

  // Epilogue. C/D: col = lane&15 (n), row = (lane>>4)*4 + r (m).
  const int quad = lane >> 4;
  if (!second) {
#pragma unroll
    for (int i = 0; i < 2; i++)
#pragma unroll
      for (int j = 0; j < 2; j++) {
        const int h = n0 + wcol * 32 + j * 16 + (lane & 15);
        const float bias = bWa[h] + bUa[h];
        const int mg0 = m0 + wrow * 32 + i * 16 + quad * 4;
        const int b = mg0 >> 7, tx0 = mg0 & 127;
        float4 o;
        o.x = (acc[i][j][0] + bias) * SCALE;
        o.y = (acc[i][j][1] + bias) * SCALE;
        o.z = (acc[i][j][2] + bias) * SCALE;
        o.w = (acc[i][j][3] + bias) * SCALE;
        *(float4*)&WcT[(size_t)b * 65536 + (size_t)h * 128 + tx0] = o;
      }
  } else {
#pragma unroll
    for (int i = 0; i < 2; i++)
#pragma unroll
      for (int j = 0; j < 2; j++) {
        const int h = n0 + wcol * 32 + j * 16 + (lane & 15);
        const int mg0 = m0 + wrow * 32 + i * 16 + quad * 4;
#pragma unroll
        for (int r = 0; r < 4; r++)
          Ux[(size_t)(mg0 + r) * 512 + h] = acc[i][j][r] * SCALE;
      }
  }
}

// ---------------------------------------------------------------------------
// k2: fused scores + softmax + cv + LayerNorm + residual.
// Block = (b, 4 ty rows), 512 threads: tx = tid&127, h-quarter = tid>>7.
// ---------------------------------------------------------------------------
__global__ __launch_bounds__(512) void attn2(
    const float* __restrict__ WcT, const float* __restrict__ Ux,
    const float* __restrict__ ctx, const float* __restrict__ xin,
    const float* __restrict__ Va,
    const float* __restrict__ gamma, const float* __restrict__ beta,
    float* __restrict__ out) {
  const int b = blockIdx.y;
  const int ty0 = blockIdx.x * 4;
  const int t = threadIdx.x;
  const int lane = t & 63, wv = t >> 6;

  __shared__ __align__(16) float s_uxp[512][4];  // [h][r], prescaled by 2
  __shared__ float s_va[512];
  __shared__ float s_part[16][128];              // [hq*4+r][tx]
  __shared__ __align__(16) float s_at[128][4];   // attn weights [tx][r]
  __shared__ float s_red[4][2][8];
  __shared__ float s_mv[4][2];

  {
    const float* uxb = Ux + (size_t)(b * 128 + ty0) * 512;
    for (int i = t; i < 2048; i += 512) {
      const int r = i >> 9, h = i & 511;
      s_uxp[h][r] = uxb[i];
    }
    s_va[t] = Va[t];  // 512 threads, 512 elems
  }
  __syncthreads();

  // ---- scores: thread owns (tx, h-quarter), 4 ty accumulators ----
  const int tx = t & 127, hq = t >> 7;
  {
    const float* wp = WcT + (size_t)b * 65536 + (size_t)hq * 128 * 128 + tx;
    const float* vap = s_va + hq * 128;
    const float4* up = (const float4*)s_uxp + hq * 128;
    float a0 = 0.f, a1 = 0.f, a2 = 0.f, a3 = 0.f;
#pragma unroll 4
    for (int hh = 0; hh < 128; hh++) {
      const float w = wp[(size_t)hh * 128];   // coalesced across tx
      const float4 u = up[hh];                // b128 broadcast
      const float va = vap[hh];               // b32 broadcast
      a0 = fmaf(va, __builtin_amdgcn_rcpf(1.0f + __expf(w + u.x)), a0);
      a1 = fmaf(va, __builtin_amdgcn_rcpf(1.0f + __expf(w + u.y)), a1);
      a2 = fmaf(va, __builtin_amdgcn_rcpf(1.0f + __expf(w + u.z)), a2);
      a3 = fmaf(va, __builtin_amdgcn_rcpf(1.0f + __expf(w + u.w)), a3);
    }
    s_part[hq * 4 + 0][tx] = a0;
    s_part[hq * 4 + 1][tx] = a1;
    s_part[hq * 4 + 2][tx] = a2;
    s_part[hq * 4 + 3][tx] = a3;
  }
  __syncthreads();

  // ---- softmax: wave r (0..3) handles ty row r ----
  if (wv < 4) {
    const int r = wv;
    float sA = -2.0f * (s_part[r][lane] + s_part[4 + r][lane] +
                        s_part[8 + r][lane] + s_part[12 + r][lane]);
    float sB = -2.0f * (s_part[r][lane + 64] + s_part[4 + r][lane + 64] +
                        s_part[8 + r][lane + 64] + s_part[12 + r][lane + 64]);
    float m = fmaxf(sA, sB);
#pragma unroll
    for (int off = 32; off; off >>= 1) m = fmaxf(m, __shfl_xor(m, off));
    const float eA = __expf(sA - m);
    const float eB = __expf(sB - m);
    float s = eA + eB;
#pragma unroll
    for (int off = 32; off; off >>= 1) s += __shfl_xor(s, off);
    const float inv = __builtin_amdgcn_rcpf(s);
    s_at[lane][r] = eA * inv;
    s_at[lane + 64][r] = eB * inv;
  }
  __syncthreads();

  // ---- context vector: thread owns d = tid for all 4 rows ----
  const int d = t;
  float cv[4] = {0.f, 0.f, 0.f, 0.f};
  {
    const float* cp = ctx + (size_t)b * 65536 + d;
#pragma unroll 4
    for (int x = 0; x < 128; x++) {
      const float c = cp[(size_t)x * 512];    // coalesced across d
      const float4 at = *(const float4*)s_at[x];
      cv[0] = fmaf(at.x, c, cv[0]);
      cv[1] = fmaf(at.y, c, cv[1]);
      cv[2] = fmaf(at.z, c, cv[2]);
      cv[3] = fmaf(at.w, c, cv[3]);
    }
  }

  // ---- layernorm stats ----
#pragma unroll
  for (int r = 0; r < 4; r++) {
    float s = cv[r], q = cv[r] * cv[r];
#pragma unroll
    for (int off = 32; off; off >>= 1) {
      s += __shfl_xor(s, off);
      q += __shfl_xor(q, off);
    }
    if (lane == 0) { s_red[r][0][wv] = s; s_red[r][1][wv] = q; }
  }
  __syncthreads();
  if (t < 4) {
    float s = 0.f, q = 0.f;
#pragma unroll
    for (int i = 0; i < 8; i++) { s += s_red[t][0][i]; q += s_red[t][1][i]; }
    const float mean = s * (1.0f / 512.0f);
    const float var = q * (1.0f / 512.0f) - mean * mean;
    s_mv[t][0] = mean;
    s_mv[t][1] = __builtin_amdgcn_rsqf(var + 1e-3f);  // keras LN eps
  }
  __syncthreads();

  // ---- normalize + gamma/beta + residual ----
  const float g = gamma[d], bb = beta[d];
#pragma unroll
  for (int r = 0; r < 4; r++) {
    const int row = b * 128 + ty0 + r;
    const float xv = xin[(size_t)row * 512 + d];
    out[(size_t)row * 512 + d] = (cv[r] - s_mv[r][0]) * s_mv[r][1] * g + bb + xv;
  }
}

extern "C" void kernel_launch(void* const* d_in, const int* in_sizes, int n_in,
                              void* d_out, int out_size, void* d_ws, size_t ws_size,
                              hipStream_t stream) {
  const float* ctx   = (const float*)d_in[0];
  const float* xin   = (const float*)d_in[1];
  const float* Wa    = (const float*)d_in[2];
  const float* bWa   = (const float*)d_in[3];
  const float* Ua    = (const float*)d_in[4];
  const float* bUa   = (const float*)d_in[5];
  const float* Va    = (const float*)d_in[6];
  // d_in[7] = bVa: additive constant on scores -> cancels in softmax.
  const float* gamma = (const float*)d_in[8];
  const float* beta  = (const float*)d_in[9];
  float* out = (float*)d_out;

  char* ws = (char*)d_ws;
  float* WcT = (float*)ws;                         // [8][512][128] fp32, 2 MB
  float* Ux  = (float*)(ws + (2u << 20));          // [1024][512]  fp32, 2 MB
  unsigned short* WaT = (unsigned short*)(ws + (4u << 20));          // 512 KB
  unsigned short* UaT = (unsigned short*)(ws + (4u << 20) + (512u << 10));

  prep_transpose<<<128, 256, 0, stream>>>(Wa, Ua, WaT, UaT);
  gemm_mfma<<<dim3(16, 8, 2), 256, 0, stream>>>(ctx, xin, WaT, UaT, bWa, bUa, WcT, Ux);
  attn2<<<dim3(32, 8), 512, 0, stream>>>(WcT, Ux, ctx, xin, Va, gamma, beta, out);
}

// Round 4
// 117.674 us; speedup vs baseline: 1.2463x; 1.0124x over previous
//
#include <hip/hip_runtime.h>

// Bahdanau attention + LayerNorm + residual, B=8, TX=TY=128, D=H=512, fp32 in/out.
//
// Pipeline:
//   k0 prep_transpose: Wa,Ua [k][n] fp32 -> WaT,UaT [n][k] bf16 bits
//   k1 gemm_mfma (bf16 MFMA 16x16x32, 64x64 tiles, 512 thr / 8 waves):
//        z=0: WcT[b][h][tx] = (ctx@Wa + bWa + bUa) * S      (transposed, prescaled)
//        z=1: Ux[b*128+ty][h] = (x@Ua) * S                  (S = 2*log2(e))
//   k2 attn3: scores s[ty,tx] = sumVa - 2*sum_h Va[h]/(1+exp2(WcT+Ux))
//        (tanh(v) = 1 - 2/(1+e^{2v}); e^{2v} = 2^{S v}; sumVa & bVa cancel in softmax)
//        -> softmax(tx) -> cv = attn@ctx -> LayerNorm*gamma+beta + x
// Harness note: dur_us carries ~86 us of un-removable overhead (two 268 MB
// d_ws poison fills @42 us visible in rocprof); our kernels are the rest.

#define SCALE 2.8853900817779268f   // 2*log2(e): e^{2v} == exp2(SCALE*v)

typedef __attribute__((ext_vector_type(8))) short short8;
typedef float floatx4 __attribute__((ext_vector_type(4)));

__device__ __forceinline__ unsigned short f2bf(float f) {
  union { float f; unsigned u; } c{f};
  unsigned r = (c.u + 0x7FFFu + ((c.u >> 16) & 1u)) >> 16;
  return (unsigned short)r;
}

// ---------------------------------------------------------------------------
// k0: transpose+convert Wa/Ua [512k][512n] fp32 -> WT [512n][512k] bf16 bits.
// 128 blocks x 256 thr; 64x64 tiles via LDS.
// ---------------------------------------------------------------------------
__global__ __launch_bounds__(256) void prep_transpose(
    const float* __restrict__ Wa, const float* __restrict__ Ua,
    unsigned short* __restrict__ WaT, unsigned short* __restrict__ UaT) {
  const int id = blockIdx.x;
  const float* __restrict__ W = (id & 64) ? Ua : Wa;
  unsigned short* __restrict__ WT = (id & 64) ? UaT : WaT;
  const int tile = id & 63;
  const int k0 = (tile >> 3) * 64;
  const int n0 = (tile & 7) * 64;
  __shared__ float tl[64][65];
  const int t = threadIdx.x;
  const int c = t & 63, r0 = t >> 6;
#pragma unroll
  for (int p = 0; p < 16; p++) {
    const int k = r0 + p * 4;
    tl[k][c] = W[(k0 + k) * 512 + n0 + c];
  }
  __syncthreads();
  const int nl = t >> 2, kc = (t & 3) * 16;
  unsigned short ov[16];
#pragma unroll
  for (int q = 0; q < 16; q++) ov[q] = f2bf(tl[kc + q][nl]);
  *(short8*)&WT[(size_t)(n0 + nl) * 512 + k0 + kc]     = *(short8*)&ov[0];
  *(short8*)&WT[(size_t)(n0 + nl) * 512 + k0 + kc + 8] = *(short8*)&ov[8];
}

// ---------------------------------------------------------------------------
// k1: dual bf16-MFMA GEMM. C[1024,512] = A[1024,512] @ B[512,512].
// 64x64 tile/block, 512 thr = 8 waves as 2(row)x4(col); wave-tile 32x16
// (2 MFMA 16x16x32). Waves 0-3 stage A (fp32->bf16), waves 4-7 stage B.
// Frag-major LDS (16B/lane slots) -> conflict-free ds_read_b128.
// ---------------------------------------------------------------------------
__global__ __launch_bounds__(512) void gemm_mfma(
    const float* __restrict__ ctx, const float* __restrict__ xin,
    const unsigned short* __restrict__ WaT, const unsigned short* __restrict__ UaT,
    const float* __restrict__ bWa, const float* __restrict__ bUa,
    float* __restrict__ WcT, float* __restrict__ Ux) {
  const bool second = (blockIdx.z != 0);
  const float* __restrict__ A = second ? xin : ctx;
  const unsigned short* __restrict__ BT = second ? UaT : WaT;
  const int m0 = blockIdx.x * 64, n0 = blockIdx.y * 64;

  __shared__ __align__(16) unsigned short As[64 * 32];
  __shared__ __align__(16) unsigned short Bs[64 * 32];

  const int t = threadIdx.x;
  const bool isA = (t < 256);
  const int s = isA ? t : (t - 256);     // staging slot 0..255
  const int sl = s & 63, sub = s >> 6;
  const int rl = sub * 16 + (sl & 15);   // local row (m for A, n for B)
  const int kl = (sl >> 4) * 8;          // k offset of this slot's frag

  const float* aptr = A + (size_t)(m0 + rl) * 512 + kl;
  const unsigned short* bptr = BT + (size_t)(n0 + rl) * 512 + kl;

  const int lane = t & 63, w = t >> 6;
  const int wrow = w & 1, wcol = w >> 1;   // 2x4 wave grid

  floatx4 acc[2] = {};

  // register double-buffer prefetch (role is wave-uniform)
  float4 a0, a1; short8 bv;
  if (isA) { a0 = *(const float4*)(aptr); a1 = *(const float4*)(aptr + 4); }
  else     { bv = *(const short8*)(bptr); }

  for (int kt = 0; kt < 512; kt += 32) {
    if (isA) {
      short8 av;
      av[0] = (short)f2bf(a0.x); av[1] = (short)f2bf(a0.y);
      av[2] = (short)f2bf(a0.z); av[3] = (short)f2bf(a0.w);
      av[4] = (short)f2bf(a1.x); av[5] = (short)f2bf(a1.y);
      av[6] = (short)f2bf(a1.z); av[7] = (short)f2bf(a1.w);
      ((short8*)As)[s] = av;
    } else {
      ((short8*)Bs)[s] = bv;
    }
    __syncthreads();
    if (kt + 32 < 512) {
      if (isA) {
        a0 = *(const float4*)(aptr + kt + 32);
        a1 = *(const float4*)(aptr + kt + 36);
      } else {
        bv = *(const short8*)(bptr + kt + 32);
      }
    }
    short8 af[2], bf;
    af[0] = ((const short8*)As)[(wrow * 2 + 0) * 64 + lane];
    af[1] = ((const short8*)As)[(wrow * 2 + 1) * 64 + lane];
    bf    = ((const short8*)Bs)[wcol * 64 + lane];
#pragma unroll
    for (int i = 0; i < 2; i++)
      acc[i] = __builtin_amdgcn_mfma_f32_16x16x32_bf16(af[i], bf, acc[i], 0, 0, 0);
    __syncthreads();
  }

  // Epilogue. C/D: col = lane&15 (n), row = (lane>>4)*4 + r (m).
  const int quad = lane >> 4;
  const int h = n0 + wcol * 16 + (lane & 15);
  if (!second) {
    const float bias = bWa[h] + bUa[h];
#pragma unroll
    for (int i = 0; i < 2; i++) {
      const int mg0 = m0 + (wrow * 2 + i) * 16 + quad * 4;
      const int b = mg0 >> 7, tx0 = mg0 & 127;
      float4 o;
      o.x = (acc[i][0] + bias) * SCALE;
      o.y = (acc[i][1] + bias) * SCALE;
      o.z = (acc[i][2] + bias) * SCALE;
      o.w = (acc[i][3] + bias) * SCALE;
      *(float4*)&WcT[(size_t)b * 65536 + (size_t)h * 128 + tx0] = o;
    }
  } else {
#pragma unroll
    for (int i = 0; i < 2; i++) {
      const int mg0 = m0 + (wrow * 2 + i) * 16 + quad * 4;
#pragma unroll
      for (int r = 0; r < 4; r++)
        Ux[(size_t)(mg0 + r) * 512 + h] = acc[i][r] * SCALE;
    }
  }
}

// ---------------------------------------------------------------------------
// k2: fused scores + softmax + cv + LayerNorm + residual.
// Block = (b, 2 ty rows), 512 threads: tx = t&127, h-quarter = t>>7.
// Grid (64,8) = 512 blocks -> 2 blocks/CU, 4 waves/SIMD.
// ---------------------------------------------------------------------------
__global__ __launch_bounds__(512) void attn3(
    const float* __restrict__ WcT, const float* __restrict__ Ux,
    const float* __restrict__ ctx, const float* __restrict__ xin,
    const float* __restrict__ Va,
    const float* __restrict__ gamma, const float* __restrict__ beta,
    float* __restrict__ out) {
  const int b = blockIdx.y;
  const int ty0 = blockIdx.x * 2;
  const int t = threadIdx.x;
  const int lane = t & 63, wv = t >> 6;

  __shared__ __align__(8) float2 s_ux[512];      // [h] -> (row0,row1), prescaled
  __shared__ float s_va[512];
  __shared__ float s_part[8][128];               // [hq*2+r][tx]
  __shared__ __align__(8) float2 s_at[128];      // attn weights [tx] -> (r0,r1)
  __shared__ float s_red[2][2][8];               // [r][sum|sq][wave]
  __shared__ float s_mv[2][2];                   // [r][mean|rstd]

  {
    const float* uxb = Ux + (size_t)(b * 128 + ty0) * 512;
    for (int i = t; i < 1024; i += 512) {
      const int r = i >> 9, h = i & 511;
      ((float*)&s_ux[h])[r] = uxb[i];
    }
    s_va[t] = Va[t];
  }
  __syncthreads();

  // ---- scores: thread owns (tx, h-quarter), 2 ty chains ----
  const int tx = t & 127, hq = t >> 7;
  {
    const float* wp = WcT + (size_t)b * 65536 + (size_t)hq * 128 * 128 + tx;
    float a0 = 0.f, a1 = 0.f;
#pragma unroll 4
    for (int hh = 0; hh < 128; hh++) {
      const float w = wp[(size_t)hh * 128];       // coalesced across tx
      const float2 u = s_ux[hq * 128 + hh];       // b64 broadcast
      const float va = s_va[hq * 128 + hh];       // b32 broadcast
      a0 = fmaf(va, __builtin_amdgcn_rcpf(1.0f + __builtin_amdgcn_exp2f(w + u.x)), a0);
      a1 = fmaf(va, __builtin_amdgcn_rcpf(1.0f + __builtin_amdgcn_exp2f(w + u.y)), a1);
    }
    s_part[hq * 2 + 0][tx] = a0;
    s_part[hq * 2 + 1][tx] = a1;
  }
  __syncthreads();

  // ---- softmax: waves 0,1 handle ty rows 0,1 ----
  if (wv < 2) {
    const int r = wv;
    float sA = -2.0f * (s_part[r][lane] + s_part[2 + r][lane] +
                        s_part[4 + r][lane] + s_part[6 + r][lane]);
    float sB = -2.0f * (s_part[r][lane + 64] + s_part[2 + r][lane + 64] +
                        s_part[4 + r][lane + 64] + s_part[6 + r][lane + 64]);
    float m = fmaxf(sA, sB);
#pragma unroll
    for (int off = 32; off; off >>= 1) m = fmaxf(m, __shfl_xor(m, off));
    const float eA = __expf(sA - m);
    const float eB = __expf(sB - m);
    float sm = eA + eB;
#pragma unroll
    for (int off = 32; off; off >>= 1) sm += __shfl_xor(sm, off);
    const float inv = __builtin_amdgcn_rcpf(sm);
    ((float*)&s_at[lane])[r] = eA * inv;
    ((float*)&s_at[lane + 64])[r] = eB * inv;
  }
  __syncthreads();

  // ---- context vector: thread owns d = t for both rows ----
  const int d = t;
  float cv0 = 0.f, cv1 = 0.f;
  {
    const float* cp = ctx + (size_t)b * 65536 + d;
#pragma unroll 4
    for (int x = 0; x < 128; x++) {
      const float c = cp[(size_t)x * 512];        // coalesced across d
      const float2 at = s_at[x];                  // b64 broadcast
      cv0 = fmaf(at.x, c, cv0);
      cv1 = fmaf(at.y, c, cv1);
    }
  }

  // ---- layernorm stats ----
#pragma unroll
  for (int r = 0; r < 2; r++) {
    const float v = r ? cv1 : cv0;
    float sm = v, q = v * v;
#pragma unroll
    for (int off = 32; off; off >>= 1) {
      sm += __shfl_xor(sm, off);
      q += __shfl_xor(q, off);
    }
    if (lane == 0) { s_red[r][0][wv] = sm; s_red[r][1][wv] = q; }
  }
  __syncthreads();
  if (t < 2) {
    float sm = 0.f, q = 0.f;
#pragma unroll
    for (int i = 0; i < 8; i++) { sm += s_red[t][0][i]; q += s_red[t][1][i]; }
    const float mean = sm * (1.0f / 512.0f);
    const float var = q * (1.0f / 512.0f) - mean * mean;
    s_mv[t][0] = mean;
    s_mv[t][1] = __builtin_amdgcn_rsqf(var + 1e-3f);  // keras LN eps
  }
  __syncthreads();

  // ---- normalize + gamma/beta + residual ----
  const float g = gamma[d], bb = beta[d];
#pragma unroll
  for (int r = 0; r < 2; r++) {
    const int row = b * 128 + ty0 + r;
    const float v = r ? cv1 : cv0;
    const float xv = xin[(size_t)row * 512 + d];
    out[(size_t)row * 512 + d] = (v - s_mv[r][0]) * s_mv[r][1] * g + bb + xv;
  }
}

extern "C" void kernel_launch(void* const* d_in, const int* in_sizes, int n_in,
                              void* d_out, int out_size, void* d_ws, size_t ws_size,
                              hipStream_t stream) {
  const float* ctx   = (const float*)d_in[0];
  const float* xin   = (const float*)d_in[1];
  const float* Wa    = (const float*)d_in[2];
  const float* bWa   = (const float*)d_in[3];
  const float* Ua    = (const float*)d_in[4];
  const float* bUa   = (const float*)d_in[5];
  const float* Va    = (const float*)d_in[6];
  // d_in[7] = bVa: additive constant on scores -> cancels in softmax.
  const float* gamma = (const float*)d_in[8];
  const float* beta  = (const float*)d_in[9];
  float* out = (float*)d_out;

  char* ws = (char*)d_ws;
  float* WcT = (float*)ws;                         // [8][512][128] fp32, 2 MB
  float* Ux  = (float*)(ws + (2u << 20));          // [1024][512]  fp32, 2 MB
  unsigned short* WaT = (unsigned short*)(ws + (4u << 20));          // 512 KB
  unsigned short* UaT = (unsigned short*)(ws + (4u << 20) + (512u << 10));

  prep_transpose<<<128, 256, 0, stream>>>(Wa, Ua, WaT, UaT);
  gemm_mfma<<<dim3(16, 8, 2), 512, 0, stream>>>(ctx, xin, WaT, UaT, bWa, bUa, WcT, Ux);
  attn3<<<dim3(64, 8), 512, 0, stream>>>(WcT, Ux, ctx, xin, Va, gamma, beta, out);
}

// Round 6
// 109.179 us; speedup vs baseline: 1.3432x; 1.0778x over previous
//
#include <hip/hip_runtime.h>

// Bahdanau attention + LayerNorm + residual, B=8, TX=TY=128, D=H=512, fp32 in/out.
//
// Two kernels (coop launch rejected silently in R5 -> plain launches):
//   k1 gemm_all (bf16 MFMA 16x16x32, 64x64 tiles, 512 thr, in-kernel B transpose
//      from fp32 W[k][n] via strided lane loads):
//        z=0: WcT[b][h][tx] = (ctx@Wa + bWa + bUa) * S   (transposed, prescaled)
//        z=1: Ux[row][h]    = (x@Ua) * S                 (S = 2*log2(e))
//   k2 attn4 (1024 thr, 4 ty rows/block, 256 blocks = 1 block/CU, 4 waves/SIMD):
//        scores -2*sum_h Va[h]/(1+exp2(WcT+Ux))
//        (tanh(v)=1-2/(1+e^{2v}); e^{2v}=2^{S v}; sumVa & bVa cancel in softmax)
//        -> softmax(tx) -> cv = attn@ctx -> LayerNorm*gamma+beta + x
// t [B,TY,TX,H] (268 MB) never materialized. Harness poison fills (2x 256 MiB,
// ~42 us each) dominate dur_us; our addressable share is ~30 us.

#define SCALE 2.8853900817779268f   // 2*log2(e): e^{2v} == exp2(SCALE*v)

typedef __attribute__((ext_vector_type(8))) short short8;
typedef float floatx4 __attribute__((ext_vector_type(4)));

__device__ __forceinline__ unsigned short f2bf(float f) {
  union { float f; unsigned u; } c{f};
  unsigned r = (c.u + 0x7FFFu + ((c.u >> 16) & 1u)) >> 16;
  return (unsigned short)r;
}

// ---------------------------------------------------------------------------
// k1: dual bf16-MFMA GEMM with inline B transpose+convert.
// C[1024,512] = A[1024,512] @ W[512,512]. 64x64 tile/block, BK=64, 8 steps.
// 512 thr = 8 waves as 4(m)x2(n); wave-tile 16m x 32n (2 MFMA / kstep).
// Frag-major LDS slots (16B/lane) -> conflict-free ds_read_b128.
// Slot s: kstep=s>>8, sub=(s>>6)&3, lane=s&63 -> row/n = sub*16+(lane&15),
//         k = kstep*32 + (lane>>4)*8.
// ---------------------------------------------------------------------------
__global__ __launch_bounds__(512) void gemm_all(
    const float* __restrict__ ctx, const float* __restrict__ xin,
    const float* __restrict__ Wa, const float* __restrict__ Ua,
    const float* __restrict__ bWa, const float* __restrict__ bUa,
    float* __restrict__ WcT, float* __restrict__ Ux) {
  const bool second = (blockIdx.z != 0);
  const float* __restrict__ A = second ? xin : ctx;
  const float* __restrict__ W = second ? Ua : Wa;   // [k][n] fp32
  const int m0 = blockIdx.x * 64, n0 = blockIdx.y * 64;

  __shared__ __align__(16) unsigned short As[512 * 8];
  __shared__ __align__(16) unsigned short Bs[512 * 8];

  const int t = threadIdx.x;
  const int lane = t & 63, wv = t >> 6;

  // staging decode (this thread fills slot t each step)
  const int skst = t >> 8;                     // kstep of my slot
  const int ssub = (t >> 6) & 3;               // 16-row/-col subtile
  const int srow = ssub * 16 + (lane & 15);    // local m (A) or n (B)
  const int sk   = skst * 32 + (lane >> 4) * 8;

  const float* aptr = A + (size_t)(m0 + srow) * 512 + sk;   // + kt
  const float* wptr = W + (size_t)sk * 512 + n0 + srow;     // + kt*512 (strided)

  const int wrow = wv & 3, wcol = wv >> 2;     // 4x2 wave grid
  floatx4 acc[2] = {};

  // register prefetch for kt=0
  float4 a0 = *(const float4*)(aptr);
  float4 a1 = *(const float4*)(aptr + 4);
  float bw[8];
#pragma unroll
  for (int j = 0; j < 8; j++) bw[j] = wptr[(size_t)j * 512];

  for (int kt = 0; kt < 512; kt += 64) {
    short8 av, bv;
    av[0] = (short)f2bf(a0.x); av[1] = (short)f2bf(a0.y);
    av[2] = (short)f2bf(a0.z); av[3] = (short)f2bf(a0.w);
    av[4] = (short)f2bf(a1.x); av[5] = (short)f2bf(a1.y);
    av[6] = (short)f2bf(a1.z); av[7] = (short)f2bf(a1.w);
#pragma unroll
    for (int j = 0; j < 8; j++) bv[j] = (short)f2bf(bw[j]);
    ((short8*)As)[t] = av;
    ((short8*)Bs)[t] = bv;
    __syncthreads();
    if (kt + 64 < 512) {
      a0 = *(const float4*)(aptr + kt + 64);
      a1 = *(const float4*)(aptr + kt + 68);
      const float* wp2 = wptr + (size_t)(kt + 64) * 512;
#pragma unroll
      for (int j = 0; j < 8; j++) bw[j] = wp2[(size_t)j * 512];
    }
#pragma unroll
    for (int ks = 0; ks < 2; ks++) {
      const short8 af  = ((const short8*)As)[ks * 256 + wrow * 64 + lane];
      const short8 bf0 = ((const short8*)Bs)[ks * 256 + (wcol * 2 + 0) * 64 + lane];
      const short8 bf1 = ((const short8*)Bs)[ks * 256 + (wcol * 2 + 1) * 64 + lane];
      acc[0] = __builtin_amdgcn_mfma_f32_16x16x32_bf16(af, bf0, acc[0], 0, 0, 0);
      acc[1] = __builtin_amdgcn_mfma_f32_16x16x32_bf16(af, bf1, acc[1], 0, 0, 0);
    }
    __syncthreads();
  }

  // Epilogue. C/D: col = lane&15 (n), row = (lane>>4)*4 + r (m).
  const int quad = lane >> 4;
  const int mg0 = m0 + wrow * 16 + quad * 4;
  if (!second) {
    const int b = mg0 >> 7, tx0 = mg0 & 127;
#pragma unroll
    for (int i = 0; i < 2; i++) {
      const int h = n0 + wcol * 32 + i * 16 + (lane & 15);
      const float bias = bWa[h] + bUa[h];
      float4 o;
      o.x = (acc[i][0] + bias) * SCALE;
      o.y = (acc[i][1] + bias) * SCALE;
      o.z = (acc[i][2] + bias) * SCALE;
      o.w = (acc[i][3] + bias) * SCALE;
      *(float4*)&WcT[(size_t)b * 65536 + (size_t)h * 128 + tx0] = o;
    }
  } else {
#pragma unroll
    for (int i = 0; i < 2; i++) {
      const int h = n0 + wcol * 32 + i * 16 + (lane & 15);
#pragma unroll
      for (int r = 0; r < 4; r++)
        Ux[(size_t)(mg0 + r) * 512 + h] = acc[i][r] * SCALE;
    }
  }
}

// ---------------------------------------------------------------------------
// k2: fused scores + softmax + cv + LayerNorm + residual.
// Block = (b, 4 ty rows), 1024 threads: tx = t&127, h-eighth = t>>7.
// Grid 256 -> 1 block/CU, 16 waves = 4 waves/SIMD.
// ---------------------------------------------------------------------------
__global__ __launch_bounds__(1024) void attn4(
    const float* __restrict__ WcT, const float* __restrict__ Ux,
    const float* __restrict__ ctx, const float* __restrict__ xin,
    const float* __restrict__ Va,
    const float* __restrict__ gamma, const float* __restrict__ beta,
    float* __restrict__ out) {
  const int b = blockIdx.x >> 5;
  const int ty0 = (blockIdx.x & 31) * 4;
  const int t = threadIdx.x;
  const int lane = t & 63, wv = t >> 6;

  __shared__ __align__(16) float4 s_ux[512];   // [h] -> rows 0..3 (prescaled)
  __shared__ float s_va[512];
  __shared__ float s_part[32][128];            // [hq*4+r][tx]
  __shared__ __align__(16) float4 s_at[128];   // attn weights [tx] -> rows
  __shared__ float s_red[4][2][8];             // [r][sum|sq][wave<8]
  __shared__ float s_mv[4][2];                 // [r][mean|rstd]

  {
    const float* uxb = Ux + (size_t)(b * 128 + ty0) * 512;
    for (int i = t; i < 2048; i += 1024) {
      const int r = i >> 9, h = i & 511;
      ((float*)&s_ux[h])[r] = uxb[i];
    }
    if (t < 512) s_va[t] = Va[t];
  }
  __syncthreads();

  // ---- scores: thread owns (tx, h-eighth), 4 ty chains ----
  const int tx = t & 127, hq = t >> 7;
  {
    const float* wp = WcT + (size_t)b * 65536 + (size_t)hq * 8192 + tx;
    float a0 = 0.f, a1 = 0.f, a2 = 0.f, a3 = 0.f;
#pragma unroll 4
    for (int hh = 0; hh < 64; hh++) {
      const float w = wp[(size_t)hh * 128];     // coalesced across tx
      const float4 u = s_ux[hq * 64 + hh];      // b128 broadcast
      const float va = s_va[hq * 64 + hh];      // b32 broadcast
      a0 = fmaf(va, __builtin_amdgcn_rcpf(1.0f + __builtin_amdgcn_exp2f(w + u.x)), a0);
      a1 = fmaf(va, __builtin_amdgcn_rcpf(1.0f + __builtin_amdgcn_exp2f(w + u.y)), a1);
      a2 = fmaf(va, __builtin_amdgcn_rcpf(1.0f + __builtin_amdgcn_exp2f(w + u.z)), a2);
      a3 = fmaf(va, __builtin_amdgcn_rcpf(1.0f + __builtin_amdgcn_exp2f(w + u.w)), a3);
    }
    s_part[hq * 4 + 0][tx] = a0;
    s_part[hq * 4 + 1][tx] = a1;
    s_part[hq * 4 + 2][tx] = a2;
    s_part[hq * 4 + 3][tx] = a3;
  }
  __syncthreads();

  // ---- softmax: waves 0..3 -> ty rows 0..3 ----
  if (wv < 4) {
    const int r = wv;
    float sA = 0.f, sB = 0.f;
#pragma unroll
    for (int q = 0; q < 8; q++) {
      sA += s_part[q * 4 + r][lane];
      sB += s_part[q * 4 + r][lane + 64];
    }
    sA *= -2.0f; sB *= -2.0f;
    float m = fmaxf(sA, sB);
#pragma unroll
    for (int off = 32; off; off >>= 1) m = fmaxf(m, __shfl_xor(m, off));
    const float eA = __expf(sA - m);
    const float eB = __expf(sB - m);
    float sm = eA + eB;
#pragma unroll
    for (int off = 32; off; off >>= 1) sm += __shfl_xor(sm, off);
    const float inv = __builtin_amdgcn_rcpf(sm);
    ((float*)&s_at[lane])[r] = eA * inv;
    ((float*)&s_at[lane + 64])[r] = eB * inv;
  }
  __syncthreads();

  // ---- context vector + LN partials: threads 0..511, d = t ----
  float cv[4] = {0.f, 0.f, 0.f, 0.f};
  if (t < 512) {
    const float* cp = ctx + (size_t)b * 65536 + t;
#pragma unroll 4
    for (int x = 0; x < 128; x++) {
      const float c = cp[(size_t)x * 512];      // coalesced across d
      const float4 at = s_at[x];                // b128 broadcast
      cv[0] = fmaf(at.x, c, cv[0]);
      cv[1] = fmaf(at.y, c, cv[1]);
      cv[2] = fmaf(at.z, c, cv[2]);
      cv[3] = fmaf(at.w, c, cv[3]);
    }
#pragma unroll
    for (int r = 0; r < 4; r++) {
      float sm = cv[r], q = cv[r] * cv[r];
#pragma unroll
      for (int off = 32; off; off >>= 1) {
        sm += __shfl_xor(sm, off);
        q += __shfl_xor(q, off);
      }
      if (lane == 0) { s_red[r][0][wv] = sm; s_red[r][1][wv] = q; }
    }
  }
  __syncthreads();
  if (t < 4) {
    float sm = 0.f, q = 0.f;
#pragma unroll
    for (int i = 0; i < 8; i++) { sm += s_red[t][0][i]; q += s_red[t][1][i]; }
    const float mean = sm * (1.0f / 512.0f);
    const float var = q * (1.0f / 512.0f) - mean * mean;
    s_mv[t][0] = mean;
    s_mv[t][1] = __builtin_amdgcn_rsqf(var + 1e-3f);  // keras LN eps
  }
  __syncthreads();

  // ---- normalize + gamma/beta + residual ----
  if (t < 512) {
    const float g = gamma[t], bb = beta[t];
#pragma unroll
    for (int r = 0; r < 4; r++) {
      const int row = b * 128 + ty0 + r;
      const float xv = xin[(size_t)row * 512 + t];
      out[(size_t)row * 512 + t] = (cv[r] - s_mv[r][0]) * s_mv[r][1] * g + bb + xv;
    }
  }
}

extern "C" void kernel_launch(void* const* d_in, const int* in_sizes, int n_in,
                              void* d_out, int out_size, void* d_ws, size_t ws_size,
                              hipStream_t stream) {
  const float* ctx   = (const float*)d_in[0];
  const float* xin   = (const float*)d_in[1];
  const float* Wa    = (const float*)d_in[2];
  const float* bWa   = (const float*)d_in[3];
  const float* Ua    = (const float*)d_in[4];
  const float* bUa   = (const float*)d_in[5];
  const float* Va    = (const float*)d_in[6];
  // d_in[7] = bVa: additive constant on scores -> cancels in softmax.
  const float* gamma = (const float*)d_in[8];
  const float* beta  = (const float*)d_in[9];
  float* out = (float*)d_out;

  char* ws = (char*)d_ws;
  float* WcT = (float*)ws;                 // [8][512][128] fp32, 2 MB
  float* Ux  = (float*)(ws + (2u << 20));  // [1024][512]  fp32, 2 MB

  gemm_all<<<dim3(16, 8, 2), 512, 0, stream>>>(ctx, xin, Wa, Ua, bWa, bUa, WcT, Ux);
  attn4<<<256, 1024, 0, stream>>>(WcT, Ux, ctx, xin, Va, gamma, beta, out);
}

// Round 8
// 108.326 us; speedup vs baseline: 1.3538x; 1.0079x over previous
//
#include <hip/hip_runtime.h>

// Bahdanau attention + LayerNorm + residual, B=8, TX=TY=128, D=H=512, fp32 in/out.
//
// Two kernels:
//   k1 gemm_all (bf16 MFMA 16x16x32, 32x64 tiles, 512 blocks = 2/CU,
//      in-kernel W transpose from fp32 [k][n], v_perm truncation fp32->bf16):
//        z=0: WcT[b][h][tx] = (ctx@Wa + bWa + bUa) * S   (transposed, prescaled)
//        z=1: Ux[row][h]    = (x@Ua) * S                 (S = 2*log2(e))
//   k2 attn4 (1024 thr, 4 ty rows/block, 256 blocks; cv/LN uses all threads):
//        scores -2*sum_h Va[h]/(1+exp2(WcT+Ux))
//        (tanh(v)=1-2/(1+e^{2v}); e^{2v}=2^{S v}; sumVa & bVa cancel in softmax)
//        -> softmax(tx) -> cv = attn@ctx -> LayerNorm*gamma+beta + x
// t [B,TY,TX,H] (268 MB) never materialized. Harness poison fills (2x 256 MiB,
// ~42 us each) dominate dur_us; addressable share ~21 us.

#define SCALE 2.8853900817779268f   // 2*log2(e): e^{2v} == exp2(SCALE*v)

typedef __attribute__((ext_vector_type(8))) short short8;
typedef float floatx4 __attribute__((ext_vector_type(4)));

// Pack hi16(lo), hi16(hi) -> one u32 (bf16 truncation; err < 2^-8 rel, fine
// vs 0.142 abs threshold). v_perm_b32: sel 0-3 = s1 bytes, 4-7 = s0 bytes.
__device__ __forceinline__ unsigned pack_bf_trunc(float lo, float hi) {
  return __builtin_amdgcn_perm(__float_as_uint(hi), __float_as_uint(lo),
                               0x07060302u);
}

// ---------------------------------------------------------------------------
// k1: dual bf16-MFMA GEMM with inline B transpose+convert.
// C[1024,512] = A[1024,512] @ W[512,512]. 32x64 tile/block, BK=128, 4 K-iters.
// 512 thr = 8 waves as 2(m)x4(n); wave-tile 16x16, 4 MFMA / K-iter.
// Frag-major LDS slots (16B/lane): A slot s -> row=((s>>6)&1)*16+(s&15),
// k=(s>>7)*32+((s&63)>>4)*8; B slot s -> n=((s>>6)&3)*16+(s&15),
// k=(s>>8)*32+((s&63)>>4)*8. Conflict-free ds_read/write_b128.
// ---------------------------------------------------------------------------
__global__ __launch_bounds__(512) void gemm_all(
    const float* __restrict__ ctx, const float* __restrict__ xin,
    const float* __restrict__ Wa, const float* __restrict__ Ua,
    const float* __restrict__ bWa, const float* __restrict__ bUa,
    float* __restrict__ WcT, float* __restrict__ Ux) {
  const bool second = (blockIdx.z != 0);
  const float* __restrict__ A = second ? xin : ctx;
  const float* __restrict__ W = second ? Ua : Wa;   // [k][n] fp32
  const int m0 = blockIdx.x * 32, n0 = blockIdx.y * 64;

  __shared__ __align__(16) unsigned short As[512 * 8];    // 8 KB
  __shared__ __align__(16) unsigned short Bs[1024 * 8];   // 16 KB

  const int t = threadIdx.x;
  const int lane = t & 63, wv = t >> 6;

  // A staging: thread t fills A-slot t
  const int arow = ((t >> 6) & 1) * 16 + (t & 15);
  const int ak   = (t >> 7) * 32 + ((t & 63) >> 4) * 8;
  const float* aptr = A + (size_t)(m0 + arow) * 512 + ak;

  // B staging: thread t fills B-slots t and t+512
  const int bn0_ = ((t >> 6) & 3) * 16 + (t & 15);
  const int bk0_ = (t >> 8) * 32 + ((t & 63) >> 4) * 8;
  const int s2 = t + 512;
  const int bn1_ = ((s2 >> 6) & 3) * 16 + (s2 & 15);
  const int bk1_ = (s2 >> 8) * 32 + ((s2 & 63) >> 4) * 8;
  const float* bptr0 = W + (size_t)bk0_ * 512 + n0 + bn0_;
  const float* bptr1 = W + (size_t)bk1_ * 512 + n0 + bn1_;

  const int wm = wv & 1, wn = wv >> 1;   // 2x4 wave grid, wave-tile 16x16
  floatx4 acc = {};

  // register prefetch for kt=0
  float4 a0 = *(const float4*)(aptr);
  float4 a1 = *(const float4*)(aptr + 4);
  float bw0[8], bw1[8];
#pragma unroll
  for (int j = 0; j < 8; j++) {
    bw0[j] = bptr0[(size_t)j * 512];
    bw1[j] = bptr1[(size_t)j * 512];
  }

  for (int kt = 0; kt < 512; kt += 128) {
    union { short8 s; uint4 u; } av, bv0, bv1;
    av.u.x = pack_bf_trunc(a0.x, a0.y);
    av.u.y = pack_bf_trunc(a0.z, a0.w);
    av.u.z = pack_bf_trunc(a1.x, a1.y);
    av.u.w = pack_bf_trunc(a1.z, a1.w);
    bv0.u.x = pack_bf_trunc(bw0[0], bw0[1]);
    bv0.u.y = pack_bf_trunc(bw0[2], bw0[3]);
    bv0.u.z = pack_bf_trunc(bw0[4], bw0[5]);
    bv0.u.w = pack_bf_trunc(bw0[6], bw0[7]);
    bv1.u.x = pack_bf_trunc(bw1[0], bw1[1]);
    bv1.u.y = pack_bf_trunc(bw1[2], bw1[3]);
    bv1.u.z = pack_bf_trunc(bw1[4], bw1[5]);
    bv1.u.w = pack_bf_trunc(bw1[6], bw1[7]);
    ((short8*)As)[t] = av.s;
    ((short8*)Bs)[t] = bv0.s;
    ((short8*)Bs)[t + 512] = bv1.s;
    __syncthreads();
    if (kt + 128 < 512) {
      a0 = *(const float4*)(aptr + kt + 128);
      a1 = *(const float4*)(aptr + kt + 132);
      const float* p0 = bptr0 + (size_t)(kt + 128) * 512;
      const float* p1 = bptr1 + (size_t)(kt + 128) * 512;
#pragma unroll
      for (int j = 0; j < 8; j++) {
        bw0[j] = p0[(size_t)j * 512];
        bw1[j] = p1[(size_t)j * 512];
      }
    }
#pragma unroll
    for (int ks = 0; ks < 4; ks++) {
      const short8 af = ((const short8*)As)[ks * 128 + wm * 64 + lane];
      const short8 bf = ((const short8*)Bs)[ks * 256 + wn * 64 + lane];
      acc = __builtin_amdgcn_mfma_f32_16x16x32_bf16(af, bf, acc, 0, 0, 0);
    }
    __syncthreads();
  }

  // Epilogue. C/D: col = lane&15 (n), row = (lane>>4)*4 + r (m).
  const int quad = lane >> 4;
  const int h = n0 + wn * 16 + (lane & 15);
  const int mg0 = m0 + wm * 16 + quad * 4;
  if (!second) {
    const float bias = bWa[h] + bUa[h];
    const int b = mg0 >> 7, tx0 = mg0 & 127;
    float4 o;
    o.x = (acc[0] + bias) * SCALE;
    o.y = (acc[1] + bias) * SCALE;
    o.z = (acc[2] + bias) * SCALE;
    o.w = (acc[3] + bias) * SCALE;
    *(float4*)&WcT[(size_t)b * 65536 + (size_t)h * 128 + tx0] = o;
  } else {
#pragma unroll
    for (int r = 0; r < 4; r++)
      Ux[(size_t)(mg0 + r) * 512 + h] = acc[r] * SCALE;
  }
}

// ---------------------------------------------------------------------------
// k2: fused scores + softmax + cv + LayerNorm + residual.
// Block = (b, 4 ty rows), 1024 threads. Score: tx = t&127, h-eighth = t>>7.
// cv/LN: d = t&511, row-pair = t>>9 (all threads busy).
// ---------------------------------------------------------------------------
__global__ __launch_bounds__(1024) void attn4(
    const float* __restrict__ WcT, const float* __restrict__ Ux,
    const float* __restrict__ ctx, const float* __restrict__ xin,
    const float* __restrict__ Va,
    const float* __restrict__ gamma, const float* __restrict__ beta,
    float* __restrict__ out) {
  const int b = blockIdx.x >> 5;
  const int ty0 = (blockIdx.x & 31) * 4;
  const int t = threadIdx.x;
  const int lane = t & 63, wv = t >> 6;

  __shared__ __align__(16) float4 s_ux[512];   // [h] -> rows 0..3 (prescaled)
  __shared__ float s_va[512];
  __shared__ float s_part[32][128];            // [hq*4+r][tx]
  __shared__ __align__(16) float4 s_at[128];   // attn weights [tx] -> rows
  __shared__ float s_red[4][2][8];             // [r][sum|sq][wave-in-half]
  __shared__ float s_mv[4][2];                 // [r][mean|rstd]

  {
    const float* uxb = Ux + (size_t)(b * 128 + ty0) * 512;
    for (int i = t; i < 2048; i += 1024) {
      const int r = i >> 9, h = i & 511;
      ((float*)&s_ux[h])[r] = uxb[i];
    }
    if (t < 512) s_va[t] = Va[t];
  }
  __syncthreads();

  // ---- scores: thread owns (tx, h-eighth), 4 ty chains ----
  const int tx = t & 127, hq = t >> 7;
  {
    const float* wp = WcT + (size_t)b * 65536 + (size_t)hq * 8192 + tx;
    float a0 = 0.f, a1 = 0.f, a2 = 0.f, a3 = 0.f;
#pragma unroll 4
    for (int hh = 0; hh < 64; hh++) {
      const float w = wp[(size_t)hh * 128];     // coalesced across tx
      const float4 u = s_ux[hq * 64 + hh];      // b128 broadcast
      const float va = s_va[hq * 64 + hh];      // b32 broadcast
      a0 = fmaf(va, __builtin_amdgcn_rcpf(1.0f + __builtin_amdgcn_exp2f(w + u.x)), a0);
      a1 = fmaf(va, __builtin_amdgcn_rcpf(1.0f + __builtin_amdgcn_exp2f(w + u.y)), a1);
      a2 = fmaf(va, __builtin_amdgcn_rcpf(1.0f + __builtin_amdgcn_exp2f(w + u.z)), a2);
      a3 = fmaf(va, __builtin_amdgcn_rcpf(1.0f + __builtin_amdgcn_exp2f(w + u.w)), a3);
    }
    s_part[hq * 4 + 0][tx] = a0;
    s_part[hq * 4 + 1][tx] = a1;
    s_part[hq * 4 + 2][tx] = a2;
    s_part[hq * 4 + 3][tx] = a3;
  }
  __syncthreads();

  // ---- softmax: waves 0..3 -> ty rows 0..3 ----
  if (wv < 4) {
    const int r = wv;
    float sA = 0.f, sB = 0.f;
#pragma unroll
    for (int q = 0; q < 8; q++) {
      sA += s_part[q * 4 + r][lane];
      sB += s_part[q * 4 + r][lane + 64];
    }
    sA *= -2.0f; sB *= -2.0f;
    float m = fmaxf(sA, sB);
#pragma unroll
    for (int off = 32; off; off >>= 1) m = fmaxf(m, __shfl_xor(m, off));
    const float eA = __expf(sA - m);
    const float eB = __expf(sB - m);
    float sm = eA + eB;
#pragma unroll
    for (int off = 32; off; off >>= 1) sm += __shfl_xor(sm, off);
    const float inv = __builtin_amdgcn_rcpf(sm);
    ((float*)&s_at[lane])[r] = eA * inv;
    ((float*)&s_at[lane + 64])[r] = eB * inv;
  }
  __syncthreads();

  // ---- context vector: thread owns (d = t&511, row-pair = t>>9) ----
  const int d = t & 511, rh = t >> 9;
  float cv0 = 0.f, cv1 = 0.f;
  {
    const float* cp = ctx + (size_t)b * 65536 + d;
#pragma unroll 4
    for (int x = 0; x < 128; x++) {
      const float c = cp[(size_t)x * 512];      // coalesced across d
      const float2 at = *(const float2*)((const float*)&s_at[x] + rh * 2);
      cv0 = fmaf(at.x, c, cv0);
      cv1 = fmaf(at.y, c, cv1);
    }
  }

  // ---- layernorm stats: rows rh*2, rh*2+1; waves 0-7 half rh=0, 8-15 rh=1
  const int wh = wv & 7;
#pragma unroll
  for (int j = 0; j < 2; j++) {
    const float v = j ? cv1 : cv0;
    float sm = v, q = v * v;
#pragma unroll
    for (int off = 32; off; off >>= 1) {
      sm += __shfl_xor(sm, off);
      q += __shfl_xor(q, off);
    }
    if (lane == 0) {
      s_red[rh * 2 + j][0][wh] = sm;
      s_red[rh * 2 + j][1][wh] = q;
    }
  }
  __syncthreads();
  if (t < 4) {
    float sm = 0.f, q = 0.f;
#pragma unroll
    for (int i = 0; i < 8; i++) { sm += s_red[t][0][i]; q += s_red[t][1][i]; }
    const float mean = sm * (1.0f / 512.0f);
    const float var = q * (1.0f / 512.0f) - mean * mean;
    s_mv[t][0] = mean;
    s_mv[t][1] = __builtin_amdgcn_rsqf(var + 1e-3f);  // keras LN eps
  }
  __syncthreads();

  // ---- normalize + gamma/beta + residual (2 rows per thread) ----
  {
    const float g = gamma[d], bb = beta[d];
#pragma unroll
    for (int j = 0; j < 2; j++) {
      const int r = rh * 2 + j;
      const int row = b * 128 + ty0 + r;
      const float v = j ? cv1 : cv0;
      const float xv = xin[(size_t)row * 512 + d];
      out[(size_t)row * 512 + d] = (v - s_mv[r][0]) * s_mv[r][1] * g + bb + xv;
    }
  }
}

extern "C" void kernel_launch(void* const* d_in, const int* in_sizes, int n_in,
                              void* d_out, int out_size, void* d_ws, size_t ws_size,
                              hipStream_t stream) {
  const float* ctx   = (const float*)d_in[0];
  const float* xin   = (const float*)d_in[1];
  const float* Wa    = (const float*)d_in[2];
  const float* bWa   = (const float*)d_in[3];
  const float* Ua    = (const float*)d_in[4];
  const float* bUa   = (const float*)d_in[5];
  const float* Va    = (const float*)d_in[6];
  // d_in[7] = bVa: additive constant on scores -> cancels in softmax.
  const float* gamma = (const float*)d_in[8];
  const float* beta  = (const float*)d_in[9];
  float* out = (float*)d_out;

  char* ws = (char*)d_ws;
  float* WcT = (float*)ws;                 // [8][512][128] fp32, 2 MB
  float* Ux  = (float*)(ws + (2u << 20));  // [1024][512]  fp32, 2 MB

  gemm_all<<<dim3(32, 8, 2), 512, 0, stream>>>(ctx, xin, Wa, Ua, bWa, bUa, WcT, Ux);
  attn4<<<256, 1024, 0, stream>>>(WcT, Ux, ctx, xin, Va, gamma, beta, out);
}